// Round 3
// baseline (838.428 us; speedup 1.0000x reference)
//
#include <hip/hip_runtime.h>
#include <hip/hip_bf16.h>

// N=50000, E=800000, F=256
// x:[N,256] ei:[2,E] W1:[256,128] b1:[128] W2:[128,12] b2:[12]
// L1:[12,512] lb1:[512] L2:[512,512] lb2:[512] L3:[512,2] lb3:[2]
// out:[N,2] fp32

// ---------------- CSR build ----------------
__global__ void k_init(int* __restrict__ deg, int* __restrict__ cursor, int n) {
    int i = blockIdx.x * blockDim.x + threadIdx.x;
    if (i < n) { deg[i] = 0; cursor[i] = 0; }
}

__global__ void k_count(const int* __restrict__ col, int* __restrict__ deg, int e) {
    int i = blockIdx.x * blockDim.x + threadIdx.x;
    if (i < e) atomicAdd(&deg[col[i]], 1);
}

__global__ void k_dinv(const int* __restrict__ deg, float* __restrict__ dinv, int n) {
    int i = blockIdx.x * blockDim.x + threadIdx.x;
    if (i < n) dinv[i] = 1.0f / sqrtf((float)deg[i] + 1.0f);  // +1 self-loop
}

// single-block exclusive scan of deg -> off
__global__ __launch_bounds__(1024)
void k_scan(const int* __restrict__ deg, int* __restrict__ off, int n) {
    __shared__ int s[1024];
    int t = threadIdx.x;
    int per = (n + 1023) >> 10;
    int start = t * per, end = min(start + per, n);
    int sum = 0;
    for (int i = start; i < end; ++i) sum += deg[i];
    s[t] = sum;
    __syncthreads();
    for (int d = 1; d < 1024; d <<= 1) {
        int v = (t >= d) ? s[t - d] : 0;
        __syncthreads();
        s[t] += v;
        __syncthreads();
    }
    int base = (t == 0) ? 0 : s[t - 1];
    for (int i = start; i < end; ++i) { off[i] = base; base += deg[i]; }
}

__global__ void k_fill(const int* __restrict__ row, const int* __restrict__ col,
                       const int* __restrict__ off, int* __restrict__ cursor,
                       int* __restrict__ nbr, int e) {
    int i = blockIdx.x * blockDim.x + threadIdx.x;
    if (i < e) {
        int c = col[i];
        int p = atomicAdd(&cursor[c], 1);
        nbr[off[c] + p] = row[i];
    }
}

// ---------------- GEMM1: t1s = (x @ W1) * dinv[r] ----------------
__global__ __launch_bounds__(256)
void k_gemm1(const float* __restrict__ A, const float* __restrict__ W,
             const float* __restrict__ dinv, float* __restrict__ t1s, int M) {
    __shared__ float xs[64][68];
    const int t  = threadIdx.x;
    const int rb = blockIdx.x * 64;
    const int cg = t & 15, rg = t >> 4;
    const int j0 = cg * 8;

    float acc[4][8] = {};
    for (int kk = 0; kk < 256; kk += 64) {
        __syncthreads();
        for (int i = t; i < 1024; i += 256) {
            int r = i >> 4, q = i & 15;
            float4 v = make_float4(0.f, 0.f, 0.f, 0.f);
            if (rb + r < M)
                v = *(const float4*)(A + (size_t)(rb + r) * 256 + kk + q * 4);
            *(float4*)(&xs[r][q * 4]) = v;
        }
        __syncthreads();
        for (int k = 0; k < 64; ++k) {
            float4 w0 = *(const float4*)(W + (size_t)(kk + k) * 128 + j0);
            float4 w1 = *(const float4*)(W + (size_t)(kk + k) * 128 + j0 + 4);
            float wv[8] = {w0.x, w0.y, w0.z, w0.w, w1.x, w1.y, w1.z, w1.w};
#pragma unroll
            for (int ri = 0; ri < 4; ++ri) {
                float xv = xs[rg * 4 + ri][k];
#pragma unroll
                for (int jj = 0; jj < 8; ++jj)
                    acc[ri][jj] = fmaf(xv, wv[jj], acc[ri][jj]);
            }
        }
    }
#pragma unroll
    for (int ri = 0; ri < 4; ++ri) {
        int r = rb + rg * 4 + ri;
        if (r < M) {
            float dv = dinv[r];
            float4 o0 = make_float4(acc[ri][0] * dv, acc[ri][1] * dv,
                                    acc[ri][2] * dv, acc[ri][3] * dv);
            float4 o1 = make_float4(acc[ri][4] * dv, acc[ri][5] * dv,
                                    acc[ri][6] * dv, acc[ri][7] * dv);
            float* p1 = t1s + (size_t)r * 128 + j0;
            *(float4*)(p1)     = o0;  *(float4*)(p1 + 4) = o1;
        }
    }
}

// ---------------- gather1 + h1 epilogue ----------------
__global__ __launch_bounds__(256)
void k_gather1(const int* __restrict__ deg, const int* __restrict__ off,
               const int* __restrict__ nbr, const float* __restrict__ t1s,
               const float* __restrict__ dinv, const float* __restrict__ b1,
               float* __restrict__ h1, int n) {
    const int lane = threadIdx.x & 63;
    const int node = blockIdx.x * 4 + (threadIdx.x >> 6);
    if (node >= n) return;
    const int dg = deg[node];
    const int o  = off[node];
    const int f0 = lane * 2;
    float2 acc = *(const float2*)(t1s + (size_t)node * 128 + f0);  // self-loop
    int i = 0;
    for (; i + 4 <= dg; i += 4) {
        int r0 = nbr[o + i], r1 = nbr[o + i + 1], r2 = nbr[o + i + 2], r3 = nbr[o + i + 3];
        float2 a0 = *(const float2*)(t1s + (size_t)r0 * 128 + f0);
        float2 a1 = *(const float2*)(t1s + (size_t)r1 * 128 + f0);
        float2 a2 = *(const float2*)(t1s + (size_t)r2 * 128 + f0);
        float2 a3 = *(const float2*)(t1s + (size_t)r3 * 128 + f0);
        acc.x += a0.x + a1.x + a2.x + a3.x;
        acc.y += a0.y + a1.y + a2.y + a3.y;
    }
    for (; i < dg; ++i) {
        int r = nbr[o + i];
        float2 a = *(const float2*)(t1s + (size_t)r * 128 + f0);
        acc.x += a.x; acc.y += a.y;
    }
    float dv = dinv[node];
    float2 b = *(const float2*)(b1 + f0);
    float2 hv;
    hv.x = fmaxf(fmaf(acc.x, dv, b.x), 0.f);
    hv.y = fmaxf(fmaf(acc.y, dv, b.y), 0.f);
    *(float2*)(h1 + (size_t)node * 128 + f0) = hv;
}

// ---------------- GEMM2: t2s = (h1 @ W2) * dinv ----------------
__global__ __launch_bounds__(256)
void k_gemm2(const float* __restrict__ h1, const float* __restrict__ W2,
             const float* __restrict__ dinv, float* __restrict__ t2s, int n) {
    __shared__ float ws[128 * 12];
    int t = threadIdx.x;
    for (int i = t; i < 128 * 12; i += 256) ws[i] = W2[i];
    __syncthreads();
    int node = blockIdx.x * 256 + t;
    if (node >= n) return;
    const float4* hp = (const float4*)(h1 + (size_t)node * 128);
    float acc[12] = {};
    for (int k4 = 0; k4 < 32; ++k4) {
        float4 hv = hp[k4];
        float h[4] = {hv.x, hv.y, hv.z, hv.w};
#pragma unroll
        for (int q = 0; q < 4; ++q) {
            int k = k4 * 4 + q;
#pragma unroll
            for (int j = 0; j < 12; ++j)
                acc[j] = fmaf(h[q], ws[k * 12 + j], acc[j]);
        }
    }
    float dv = dinv[node];
    float* p1 = t2s + (size_t)node * 12;
#pragma unroll
    for (int j = 0; j < 12; ++j) p1[j] = acc[j] * dv;
}

// ---------------- fused MLP: gather2+h2 -> 12->512 -> 512->512 -> 512->2 ----------------
// 32 nodes per block, 256 threads. Each thread: 2 cols x 32 nodes in layer 2.
__global__ __launch_bounds__(256, 2)
void k_mlp(const int* __restrict__ deg, const int* __restrict__ off,
           const int* __restrict__ nbr, const float* __restrict__ t2s,
           const float* __restrict__ dinv, const float* __restrict__ b2,
           const float* __restrict__ L1, const float* __restrict__ lb1,
           const float* __restrict__ L2w, const float* __restrict__ lb2,
           const float* __restrict__ L3, const float* __restrict__ lb3,
           float* __restrict__ out, int n) {
    __shared__ float h2s[32][13];        // +1 pad -> conflict-free column reads
    __shared__ float h3t[512][32];       // k-major: h3t[k][ni]
    __shared__ float2 parts[4][32];      // per-wave partial outputs
    const int t  = threadIdx.x;
    const int nb = blockIdx.x * 32;

    // ---- phase 0: gather2 + h2 = relu(dinv*(t2s[self]+sum t2s[nbr]) + b2)
    for (int idx = t; idx < 384; idx += 256) {
        int ni = idx / 12, j = idx % 12;
        int node = nb + ni;
        float v = 0.f;
        if (node < n) {
            int dg = deg[node], o = off[node];
            float acc = t2s[(size_t)node * 12 + j];   // self-loop
            for (int i = 0; i < dg; ++i) {
                int r = nbr[o + i];
                acc += t2s[(size_t)r * 12 + j];
            }
            v = fmaxf(fmaf(acc, dinv[node], b2[j]), 0.f);
        }
        h2s[ni][j] = v;
    }
    __syncthreads();

    // ---- phase 1: h3t[j][ni] = relu(h2 @ L1 + lb1); thread owns ni = t&31
    {
        const int ni = t & 31;
        const int jg = t >> 5;           // 0..7
        float h2r[12];
#pragma unroll
        for (int k = 0; k < 12; ++k) h2r[k] = h2s[ni][k];
        for (int i = 0; i < 64; ++i) {
            int j = i * 8 + jg;
            float acc = lb1[j];
#pragma unroll
            for (int k = 0; k < 12; ++k)
                acc = fmaf(h2r[k], L1[k * 512 + j], acc);
            h3t[j][ni] = fmaxf(acc, 0.f);
        }
    }
    __syncthreads();

    // ---- phase 2: layer 2, each thread 2 cols (j0=2t) x 32 nodes
    float2 acc[32];
#pragma unroll
    for (int i = 0; i < 32; ++i) acc[i] = make_float2(0.f, 0.f);
    const int j0 = (t & 255) << 1;
    const float* wrow = L2w + j0;
#pragma unroll 2
    for (int k = 0; k < 512; ++k) {
        float2 w = *(const float2*)(wrow + (size_t)k * 512);
        const float4* hp = (const float4*)(&h3t[k][0]);
#pragma unroll
        for (int q = 0; q < 8; ++q) {
            float4 hv = hp[q];
            acc[q * 4 + 0].x = fmaf(hv.x, w.x, acc[q * 4 + 0].x);
            acc[q * 4 + 0].y = fmaf(hv.x, w.y, acc[q * 4 + 0].y);
            acc[q * 4 + 1].x = fmaf(hv.y, w.x, acc[q * 4 + 1].x);
            acc[q * 4 + 1].y = fmaf(hv.y, w.y, acc[q * 4 + 1].y);
            acc[q * 4 + 2].x = fmaf(hv.z, w.x, acc[q * 4 + 2].x);
            acc[q * 4 + 2].y = fmaf(hv.z, w.y, acc[q * 4 + 2].y);
            acc[q * 4 + 3].x = fmaf(hv.w, w.x, acc[q * 4 + 3].x);
            acc[q * 4 + 3].y = fmaf(hv.w, w.y, acc[q * 4 + 3].y);
        }
    }

    // ---- phase 3: h4 = relu(acc + lb2), contract with L3 -> per-thread partials
    {
        float bb0 = lb2[j0], bb1 = lb2[j0 + 1];
        float2 l30 = *(const float2*)(L3 + j0 * 2);
        float2 l31 = *(const float2*)(L3 + (j0 + 1) * 2);
#pragma unroll
        for (int ni = 0; ni < 32; ++ni) {
            float a = fmaxf(acc[ni].x + bb0, 0.f);
            float b = fmaxf(acc[ni].y + bb1, 0.f);
            acc[ni].x = fmaf(a, l30.x, b * l31.x);
            acc[ni].y = fmaf(a, l30.y, b * l31.y);
        }
    }
    // wave reduce (64 lanes = 64 of the 512 cols handled per wave)
#pragma unroll
    for (int ofs = 32; ofs; ofs >>= 1) {
#pragma unroll
        for (int ni = 0; ni < 32; ++ni) {
            acc[ni].x += __shfl_xor(acc[ni].x, ofs, 64);
            acc[ni].y += __shfl_xor(acc[ni].y, ofs, 64);
        }
    }
    const int lane = t & 63, wv = t >> 6;
    if (lane == 0) {
#pragma unroll
        for (int ni = 0; ni < 32; ++ni) parts[wv][ni] = acc[ni];
    }
    __syncthreads();
    if (t < 64) {
        int ni = t >> 1, c = t & 1;
        int node = nb + ni;
        if (node < n) {
            const float* pb = (const float*)parts;
            float s = pb[0 * 64 + ni * 2 + c] + pb[1 * 64 + ni * 2 + c]
                    + pb[2 * 64 + ni * 2 + c] + pb[3 * 64 + ni * 2 + c];
            out[(size_t)node * 2 + c] = s + lb3[c];
        }
    }
}

extern "C" void kernel_launch(void* const* d_in, const int* in_sizes, int n_in,
                              void* d_out, int out_size, void* d_ws, size_t ws_size,
                              hipStream_t stream) {
    const float* x   = (const float*)d_in[0];
    const int*   ei  = (const int*)d_in[1];
    const float* W1  = (const float*)d_in[2];
    const float* b1  = (const float*)d_in[3];
    const float* W2  = (const float*)d_in[4];
    const float* b2  = (const float*)d_in[5];
    const float* L1  = (const float*)d_in[6];
    const float* lb1 = (const float*)d_in[7];
    const float* L2w = (const float*)d_in[8];
    const float* lb2 = (const float*)d_in[9];
    const float* L3  = (const float*)d_in[10];
    const float* lb3 = (const float*)d_in[11];
    float* out = (float*)d_out;

    const int N = in_sizes[0] / 256;
    const int E = in_sizes[1] / 2;
    const int* rowp = ei;       // edge_index[0]
    const int* colp = ei + E;   // edge_index[1]

    char* ws = (char*)d_ws;
    int*   deg    = (int*)ws;                       // N
    int*   cursor = deg + N;                        // N
    int*   offp   = cursor + N;                     // N
    float* dinv   = (float*)(offp + N);             // N
    int*   nbr    = (int*)(dinv + N);               // E
    float* t1s    = (float*)(nbr + E);              // N*128
    float* h1     = t1s + (size_t)N * 128;          // N*128
    float* t2s    = h1 + (size_t)N * 128;           // N*12

    k_init  <<<(N + 255) / 256, 256, 0, stream>>>(deg, cursor, N);
    k_count <<<(E + 255) / 256, 256, 0, stream>>>(colp, deg, E);
    k_dinv  <<<(N + 255) / 256, 256, 0, stream>>>(deg, dinv, N);
    k_scan  <<<1, 1024, 0, stream>>>(deg, offp, N);
    k_fill  <<<(E + 255) / 256, 256, 0, stream>>>(rowp, colp, offp, cursor, nbr, E);

    k_gemm1   <<<(N + 63) / 64, 256, 0, stream>>>(x, W1, dinv, t1s, N);
    k_gather1 <<<(N + 3) / 4, 256, 0, stream>>>(deg, offp, nbr, t1s, dinv, b1, h1, N);
    k_gemm2   <<<(N + 255) / 256, 256, 0, stream>>>(h1, W2, dinv, t2s, N);
    k_mlp     <<<(N + 31) / 32, 256, 0, stream>>>(deg, offp, nbr, t2s, dinv, b2,
                                                  L1, lb1, L2w, lb2, L3, lb3, out, N);
}

// Round 4
// 789.002 us; speedup vs baseline: 1.0626x; 1.0626x over previous
//
#include <hip/hip_runtime.h>
#include <hip/hip_bf16.h>

// N=50000, E=800000, F=256
// x:[N,256] ei:[2,E] W1:[256,128] b1:[128] W2:[128,12] b2:[12]
// L1:[12,512] lb1:[512] L2:[512,512] lb2:[512] L3:[512,2] lb3:[2]
// out:[N,2] fp32

typedef short short8 __attribute__((ext_vector_type(8)));
typedef float f32x4 __attribute__((ext_vector_type(4)));

static __device__ __forceinline__ unsigned short f2bf(float f) {
    unsigned int u = __float_as_uint(f);
    u = (u + 0x7FFF + ((u >> 16) & 1)) >> 16;   // round-to-nearest-even
    return (unsigned short)u;
}
static __device__ __forceinline__ float bf2f(unsigned short s) {
    return __uint_as_float((unsigned int)s << 16);
}

// ---------------- CSR build ----------------
__global__ void k_init(int* __restrict__ deg, int* __restrict__ cursor, int n) {
    int i = blockIdx.x * blockDim.x + threadIdx.x;
    if (i < n) { deg[i] = 0; cursor[i] = 0; }
}

__global__ void k_count(const int* __restrict__ col, int* __restrict__ deg, int e) {
    int i = blockIdx.x * blockDim.x + threadIdx.x;
    if (i < e) atomicAdd(&deg[col[i]], 1);
}

__global__ void k_dinv(const int* __restrict__ deg, float* __restrict__ dinv, int n) {
    int i = blockIdx.x * blockDim.x + threadIdx.x;
    if (i < n) dinv[i] = 1.0f / sqrtf((float)deg[i] + 1.0f);  // +1 self-loop
}

__global__ __launch_bounds__(1024)
void k_scan(const int* __restrict__ deg, int* __restrict__ off, int n) {
    __shared__ int s[1024];
    int t = threadIdx.x;
    int per = (n + 1023) >> 10;
    int start = t * per, end = min(start + per, n);
    int sum = 0;
    for (int i = start; i < end; ++i) sum += deg[i];
    s[t] = sum;
    __syncthreads();
    for (int d = 1; d < 1024; d <<= 1) {
        int v = (t >= d) ? s[t - d] : 0;
        __syncthreads();
        s[t] += v;
        __syncthreads();
    }
    int base = (t == 0) ? 0 : s[t - 1];
    for (int i = start; i < end; ++i) { off[i] = base; base += deg[i]; }
}

__global__ void k_fill(const int* __restrict__ row, const int* __restrict__ col,
                       const int* __restrict__ off, int* __restrict__ cursor,
                       int* __restrict__ nbr, int e) {
    int i = blockIdx.x * blockDim.x + threadIdx.x;
    if (i < e) {
        int c = col[i];
        int p = atomicAdd(&cursor[c], 1);
        nbr[off[c] + p] = row[i];
    }
}

// ---------------- L2 -> transposed bf16 hi/lo split ----------------
__global__ void k_cvtL2(const float* __restrict__ L2w,
                        short* __restrict__ L2hi, short* __restrict__ L2lo) {
    int col = blockIdx.x;   // 512 blocks
    for (int k = threadIdx.x; k < 512; k += 256) {
        float v = L2w[(size_t)k * 512 + col];
        unsigned short hb = f2bf(v);
        float hf = bf2f(hb);
        unsigned short lb = f2bf(v - hf);
        L2hi[(size_t)col * 512 + k] = (short)hb;
        L2lo[(size_t)col * 512 + k] = (short)lb;
    }
}

// ---------------- GEMM1: t1s = (x @ W1) * dinv[r] ----------------
__global__ __launch_bounds__(256)
void k_gemm1(const float* __restrict__ A, const float* __restrict__ W,
             const float* __restrict__ dinv, float* __restrict__ t1s, int M) {
    __shared__ float xs[64][68];
    const int t  = threadIdx.x;
    const int rb = blockIdx.x * 64;
    const int cg = t & 15, rg = t >> 4;
    const int j0 = cg * 8;

    float acc[4][8] = {};
    for (int kk = 0; kk < 256; kk += 64) {
        __syncthreads();
        for (int i = t; i < 1024; i += 256) {
            int r = i >> 4, q = i & 15;
            float4 v = make_float4(0.f, 0.f, 0.f, 0.f);
            if (rb + r < M)
                v = *(const float4*)(A + (size_t)(rb + r) * 256 + kk + q * 4);
            *(float4*)(&xs[r][q * 4]) = v;
        }
        __syncthreads();
        for (int k = 0; k < 64; ++k) {
            float4 w0 = *(const float4*)(W + (size_t)(kk + k) * 128 + j0);
            float4 w1 = *(const float4*)(W + (size_t)(kk + k) * 128 + j0 + 4);
            float wv[8] = {w0.x, w0.y, w0.z, w0.w, w1.x, w1.y, w1.z, w1.w};
#pragma unroll
            for (int ri = 0; ri < 4; ++ri) {
                float xv = xs[rg * 4 + ri][k];
#pragma unroll
                for (int jj = 0; jj < 8; ++jj)
                    acc[ri][jj] = fmaf(xv, wv[jj], acc[ri][jj]);
            }
        }
    }
#pragma unroll
    for (int ri = 0; ri < 4; ++ri) {
        int r = rb + rg * 4 + ri;
        if (r < M) {
            float dv = dinv[r];
            float4 o0 = make_float4(acc[ri][0] * dv, acc[ri][1] * dv,
                                    acc[ri][2] * dv, acc[ri][3] * dv);
            float4 o1 = make_float4(acc[ri][4] * dv, acc[ri][5] * dv,
                                    acc[ri][6] * dv, acc[ri][7] * dv);
            float* p1 = t1s + (size_t)r * 128 + j0;
            *(float4*)(p1)     = o0;  *(float4*)(p1 + 4) = o1;
        }
    }
}

// ---------------- gather1 + h1 epilogue ----------------
__global__ __launch_bounds__(256)
void k_gather1(const int* __restrict__ deg, const int* __restrict__ off,
               const int* __restrict__ nbr, const float* __restrict__ t1s,
               const float* __restrict__ dinv, const float* __restrict__ b1,
               float* __restrict__ h1, int n) {
    const int lane = threadIdx.x & 63;
    const int node = blockIdx.x * 4 + (threadIdx.x >> 6);
    if (node >= n) return;
    const int dg = deg[node];
    const int o  = off[node];
    const int f0 = lane * 2;
    float2 acc = *(const float2*)(t1s + (size_t)node * 128 + f0);  // self-loop
    int i = 0;
    for (; i + 4 <= dg; i += 4) {
        int r0 = nbr[o + i], r1 = nbr[o + i + 1], r2 = nbr[o + i + 2], r3 = nbr[o + i + 3];
        float2 a0 = *(const float2*)(t1s + (size_t)r0 * 128 + f0);
        float2 a1 = *(const float2*)(t1s + (size_t)r1 * 128 + f0);
        float2 a2 = *(const float2*)(t1s + (size_t)r2 * 128 + f0);
        float2 a3 = *(const float2*)(t1s + (size_t)r3 * 128 + f0);
        acc.x += a0.x + a1.x + a2.x + a3.x;
        acc.y += a0.y + a1.y + a2.y + a3.y;
    }
    for (; i < dg; ++i) {
        int r = nbr[o + i];
        float2 a = *(const float2*)(t1s + (size_t)r * 128 + f0);
        acc.x += a.x; acc.y += a.y;
    }
    float dv = dinv[node];
    float2 b = *(const float2*)(b1 + f0);
    float2 hv;
    hv.x = fmaxf(fmaf(acc.x, dv, b.x), 0.f);
    hv.y = fmaxf(fmaf(acc.y, dv, b.y), 0.f);
    *(float2*)(h1 + (size_t)node * 128 + f0) = hv;
}

// ---------------- GEMM2: t2s = (h1 @ W2) * dinv ----------------
__global__ __launch_bounds__(256)
void k_gemm2(const float* __restrict__ h1, const float* __restrict__ W2,
             const float* __restrict__ dinv, float* __restrict__ t2s, int n) {
    __shared__ float ws[128 * 12];
    int t = threadIdx.x;
    for (int i = t; i < 128 * 12; i += 256) ws[i] = W2[i];
    __syncthreads();
    int node = blockIdx.x * 256 + t;
    if (node >= n) return;
    const float4* hp = (const float4*)(h1 + (size_t)node * 128);
    float acc[12] = {};
    for (int k4 = 0; k4 < 32; ++k4) {
        float4 hv = hp[k4];
        float h[4] = {hv.x, hv.y, hv.z, hv.w};
#pragma unroll
        for (int q = 0; q < 4; ++q) {
            int k = k4 * 4 + q;
#pragma unroll
            for (int j = 0; j < 12; ++j)
                acc[j] = fmaf(h[q], ws[k * 12 + j], acc[j]);
        }
    }
    float dv = dinv[node];
    float* p1 = t2s + (size_t)node * 12;
#pragma unroll
    for (int j = 0; j < 12; ++j) p1[j] = acc[j] * dv;
}

// ---------------- fused MLP with split-bf16 MFMA for layer 2 ----------------
// 64 nodes/block, 256 threads (4 waves x 128 cols).
// Layer2 GEMM: C[64x512] = h3[64x512] @ L2[512x512] via
// A_hi*B_hi + A_lo*B_hi + A_hi*B_lo (bf16 MFMA 16x16x32, fp32 acc).
__global__ __launch_bounds__(256, 2)
void k_mlp(const int* __restrict__ deg, const int* __restrict__ off,
           const int* __restrict__ nbr, const float* __restrict__ t2s,
           const float* __restrict__ dinv, const float* __restrict__ b2,
           const float* __restrict__ L1, const float* __restrict__ lb1,
           const short* __restrict__ L2hi, const short* __restrict__ L2lo,
           const float* __restrict__ lb2,
           const float* __restrict__ L3, const float* __restrict__ lb3,
           float* __restrict__ out, int n) {
    __shared__ float h2s[64][13];
    __shared__ short Ahi[64 * 128];      // h3 chunk, bf16 hi, XOR-swizzled
    __shared__ short Alo[64 * 128];      // h3 chunk, bf16 lo
    __shared__ float parts[4][64][2];
    const int t  = threadIdx.x;
    const int nb = blockIdx.x * 64;

    // ---- phase 0: gather2 + h2 = relu(dinv*(t2s[self]+sum t2s[nbr]) + b2)
    for (int idx = t; idx < 768; idx += 256) {
        int ni = idx / 12, j = idx % 12;
        int node = nb + ni;
        float v = 0.f;
        if (node < n) {
            int dg = deg[node], o = off[node];
            float acc = t2s[(size_t)node * 12 + j];   // self-loop
            for (int i = 0; i < dg; ++i)
                acc += t2s[(size_t)nbr[o + i] * 12 + j];
            v = fmaxf(fmaf(acc, dinv[node], b2[j]), 0.f);
        }
        h2s[ni][j] = v;
    }
    __syncthreads();

    const int lane = t & 63, wid = t >> 6;
    const int wcb  = wid * 128;          // wave's column base
    const int p1node = t >> 2, p1jg = t & 3;

    float h2r[12];
#pragma unroll
    for (int q = 0; q < 12; ++q) h2r[q] = h2s[p1node][q];

    f32x4 acc[4][8];
#pragma unroll
    for (int mt = 0; mt < 4; ++mt)
#pragma unroll
        for (int nf = 0; nf < 8; ++nf) acc[mt][nf] = 0.f;

    for (int ch = 0; ch < 4; ++ch) {
        const int cb = ch * 128;
        // ---- phase 1: h3 chunk -> bf16 hi/lo in swizzled LDS
        // thread computes j = cb + p1jg*32 + [0,32) for node p1node
#pragma unroll
        for (int i8 = 0; i8 < 4; ++i8) {
            const int j0 = cb + p1jg * 32 + i8 * 8;
            float4 a0 = *(const float4*)(lb1 + j0);
            float4 a1 = *(const float4*)(lb1 + j0 + 4);
            float v[8] = {a0.x, a0.y, a0.z, a0.w, a1.x, a1.y, a1.z, a1.w};
#pragma unroll
            for (int q = 0; q < 12; ++q) {
                float4 w0 = *(const float4*)(L1 + q * 512 + j0);
                float4 w1 = *(const float4*)(L1 + q * 512 + j0 + 4);
                float hq = h2r[q];
                v[0] = fmaf(hq, w0.x, v[0]); v[1] = fmaf(hq, w0.y, v[1]);
                v[2] = fmaf(hq, w0.z, v[2]); v[3] = fmaf(hq, w0.w, v[3]);
                v[4] = fmaf(hq, w1.x, v[4]); v[5] = fmaf(hq, w1.y, v[5]);
                v[6] = fmaf(hq, w1.z, v[6]); v[7] = fmaf(hq, w1.w, v[7]);
            }
            short8 hv, lv;
#pragma unroll
            for (int e = 0; e < 8; ++e) {
                float f = fmaxf(v[e], 0.f);
                unsigned short hb = f2bf(f);
                float hf = bf2f(hb);
                unsigned short lb = f2bf(f - hf);
                hv[e] = (short)hb; lv[e] = (short)lb;
            }
            const int wb = p1node * 256 + ((p1jg * 64 + i8 * 16) ^ ((p1node & 7) << 4));
            *(short8*)((char*)Ahi + wb) = hv;
            *(short8*)((char*)Alo + wb) = lv;
        }
        __syncthreads();

        // ---- phase 2: MFMA over this K-chunk (4 k-steps of 32)
#pragma unroll
        for (int ks = 0; ks < 4; ++ks) {
            short8 ah[4], al[4];
            const int abase = ks * 64 + ((lane >> 4) << 4);   // byte within row
#pragma unroll
            for (int mt = 0; mt < 4; ++mt) {
                int row = mt * 16 + (lane & 15);
                int boff = row * 256 + (abase ^ ((row & 7) << 4));
                ah[mt] = *(const short8*)((const char*)Ahi + boff);
                al[mt] = *(const short8*)((const char*)Alo + boff);
            }
            const int kg = cb + ks * 32 + ((lane >> 4) << 3);
#pragma unroll
            for (int h = 0; h < 2; ++h) {
                short8 bh[4], bl[4];
#pragma unroll
                for (int f = 0; f < 4; ++f) {
                    int col = wcb + (h * 4 + f) * 16 + (lane & 15);
                    bh[f] = *(const short8*)(L2hi + (size_t)col * 512 + kg);
                    bl[f] = *(const short8*)(L2lo + (size_t)col * 512 + kg);
                }
#pragma unroll
                for (int f = 0; f < 4; ++f) {
#pragma unroll
                    for (int mt = 0; mt < 4; ++mt) {
                        f32x4 a = acc[mt][h * 4 + f];
                        a = __builtin_amdgcn_mfma_f32_16x16x32_bf16(ah[mt], bh[f], a, 0, 0, 0);
                        a = __builtin_amdgcn_mfma_f32_16x16x32_bf16(al[mt], bh[f], a, 0, 0, 0);
                        a = __builtin_amdgcn_mfma_f32_16x16x32_bf16(ah[mt], bl[f], a, 0, 0, 0);
                        acc[mt][h * 4 + f] = a;
                    }
                }
            }
        }
        __syncthreads();
    }

    // ---- epilogue: h4 = relu(acc + lb2), out-partial = h4 @ L3
    float po[4][4][2];
#pragma unroll
    for (int mt = 0; mt < 4; ++mt)
#pragma unroll
        for (int r = 0; r < 4; ++r) { po[mt][r][0] = 0.f; po[mt][r][1] = 0.f; }
#pragma unroll
    for (int nf = 0; nf < 8; ++nf) {
        int col = wcb + nf * 16 + (lane & 15);
        float bb = lb2[col];
        float2 l3 = *(const float2*)(L3 + (size_t)col * 2);
#pragma unroll
        for (int mt = 0; mt < 4; ++mt)
#pragma unroll
            for (int r = 0; r < 4; ++r) {
                float h4 = fmaxf(acc[mt][nf][r] + bb, 0.f);
                po[mt][r][0] = fmaf(h4, l3.x, po[mt][r][0]);
                po[mt][r][1] = fmaf(h4, l3.y, po[mt][r][1]);
            }
    }
    // reduce over the 16 col-lanes (lane&15); stays within lane>>4 group
#pragma unroll
    for (int ofs = 1; ofs <= 8; ofs <<= 1) {
#pragma unroll
        for (int mt = 0; mt < 4; ++mt)
#pragma unroll
            for (int r = 0; r < 4; ++r) {
                po[mt][r][0] += __shfl_xor(po[mt][r][0], ofs, 64);
                po[mt][r][1] += __shfl_xor(po[mt][r][1], ofs, 64);
            }
    }
    const int g = lane >> 4;
    if ((lane & 15) == 0) {
#pragma unroll
        for (int mt = 0; mt < 4; ++mt)
#pragma unroll
            for (int r = 0; r < 4; ++r) {
                parts[wid][mt * 16 + g * 4 + r][0] = po[mt][r][0];
                parts[wid][mt * 16 + g * 4 + r][1] = po[mt][r][1];
            }
    }
    __syncthreads();
    if (t < 128) {
        int nl = t >> 1, c = t & 1;
        int node = nb + nl;
        if (node < n)
            out[(size_t)node * 2 + c] = parts[0][nl][c] + parts[1][nl][c]
                                      + parts[2][nl][c] + parts[3][nl][c] + lb3[c];
    }
}

extern "C" void kernel_launch(void* const* d_in, const int* in_sizes, int n_in,
                              void* d_out, int out_size, void* d_ws, size_t ws_size,
                              hipStream_t stream) {
    const float* x   = (const float*)d_in[0];
    const int*   ei  = (const int*)d_in[1];
    const float* W1  = (const float*)d_in[2];
    const float* b1  = (const float*)d_in[3];
    const float* W2  = (const float*)d_in[4];
    const float* b2  = (const float*)d_in[5];
    const float* L1  = (const float*)d_in[6];
    const float* lb1 = (const float*)d_in[7];
    const float* L2w = (const float*)d_in[8];
    const float* lb2 = (const float*)d_in[9];
    const float* L3  = (const float*)d_in[10];
    const float* lb3 = (const float*)d_in[11];
    float* out = (float*)d_out;

    const int N = in_sizes[0] / 256;
    const int E = in_sizes[1] / 2;
    const int* rowp = ei;       // edge_index[0]
    const int* colp = ei + E;   // edge_index[1]

    char* ws = (char*)d_ws;
    int*   deg    = (int*)ws;                       // N
    int*   cursor = deg + N;                        // N
    int*   offp   = cursor + N;                     // N
    float* dinv   = (float*)(offp + N);             // N
    int*   nbr    = (int*)(dinv + N);               // E
    float* t1s    = (float*)(nbr + E);              // N*128
    float* h1     = t1s + (size_t)N * 128;          // N*128
    float* t2s    = h1 + (size_t)N * 128;           // N*12
    short* L2hi   = (short*)(t2s + (size_t)N * 12); // 512*512
    short* L2lo   = L2hi + 512 * 512;               // 512*512

    k_init  <<<(N + 255) / 256, 256, 0, stream>>>(deg, cursor, N);
    k_count <<<(E + 255) / 256, 256, 0, stream>>>(colp, deg, E);
    k_dinv  <<<(N + 255) / 256, 256, 0, stream>>>(deg, dinv, N);
    k_scan  <<<1, 1024, 0, stream>>>(deg, offp, N);
    k_fill  <<<(E + 255) / 256, 256, 0, stream>>>(rowp, colp, offp, cursor, nbr, E);
    k_cvtL2 <<<512, 256, 0, stream>>>(L2w, L2hi, L2lo);

    k_gemm1   <<<(N + 63) / 64, 256, 0, stream>>>(x, W1, dinv, t1s, N);
    k_gather1 <<<(N + 3) / 4, 256, 0, stream>>>(deg, offp, nbr, t1s, dinv, b1, h1, N);
    k_gemm2   <<<(N + 255) / 256, 256, 0, stream>>>(h1, W2, dinv, t2s, N);
    k_mlp     <<<(N + 63) / 64, 256, 0, stream>>>(deg, offp, nbr, t2s, dinv, b2,
                                                  L1, lb1, L2hi, L2lo, lb2,
                                                  L3, lb3, out, N);
}

// Round 5
// 706.321 us; speedup vs baseline: 1.1870x; 1.1171x over previous
//
#include <hip/hip_runtime.h>
#include <hip/hip_bf16.h>

// N=50000, E=800000, F=256
// x:[N,256] ei:[2,E] W1:[256,128] b1:[128] W2:[128,12] b2:[12]
// L1:[12,512] lb1:[512] L2:[512,512] lb2:[512] L3:[512,2] lb3:[2]
// out:[N,2] fp32

typedef short short8 __attribute__((ext_vector_type(8)));
typedef float f32x4 __attribute__((ext_vector_type(4)));

static __device__ __forceinline__ unsigned short f2bf(float f) {
    unsigned int u = __float_as_uint(f);
    u = (u + 0x7FFF + ((u >> 16) & 1)) >> 16;   // round-to-nearest-even
    return (unsigned short)u;
}
static __device__ __forceinline__ float bf2f(unsigned short s) {
    return __uint_as_float((unsigned int)s << 16);
}

// ---------------- CSR build ----------------
__global__ void k_init(int* __restrict__ deg, int* __restrict__ cursor, int n) {
    int i = blockIdx.x * blockDim.x + threadIdx.x;
    if (i < n) { deg[i] = 0; cursor[i] = 0; }
}

__global__ void k_count(const int* __restrict__ col, int* __restrict__ deg, int e) {
    int i = blockIdx.x * blockDim.x + threadIdx.x;
    if (i < e) atomicAdd(&deg[col[i]], 1);
}

__global__ void k_dinv(const int* __restrict__ deg, float* __restrict__ dinv, int n) {
    int i = blockIdx.x * blockDim.x + threadIdx.x;
    if (i < n) dinv[i] = 1.0f / sqrtf((float)deg[i] + 1.0f);  // +1 self-loop
}

__global__ __launch_bounds__(1024)
void k_scan(const int* __restrict__ deg, int* __restrict__ off, int n) {
    __shared__ int s[1024];
    int t = threadIdx.x;
    int per = (n + 1023) >> 10;
    int start = t * per, end = min(start + per, n);
    int sum = 0;
    for (int i = start; i < end; ++i) sum += deg[i];
    s[t] = sum;
    __syncthreads();
    for (int d = 1; d < 1024; d <<= 1) {
        int v = (t >= d) ? s[t - d] : 0;
        __syncthreads();
        s[t] += v;
        __syncthreads();
    }
    int base = (t == 0) ? 0 : s[t - 1];
    for (int i = start; i < end; ++i) { off[i] = base; base += deg[i]; }
}

__global__ void k_fill(const int* __restrict__ row, const int* __restrict__ col,
                       const int* __restrict__ off, int* __restrict__ cursor,
                       int* __restrict__ nbr, int e) {
    int i = blockIdx.x * blockDim.x + threadIdx.x;
    if (i < e) {
        int c = col[i];
        int p = atomicAdd(&cursor[c], 1);
        nbr[off[c] + p] = row[i];
    }
}

// ---------------- L2 -> transposed bf16 hi/lo split ----------------
__global__ void k_cvtL2(const float* __restrict__ L2w,
                        short* __restrict__ L2hi, short* __restrict__ L2lo) {
    int col = blockIdx.x;   // 512 blocks
    for (int k = threadIdx.x; k < 512; k += 256) {
        float v = L2w[(size_t)k * 512 + col];
        unsigned short hb = f2bf(v);
        float hf = bf2f(hb);
        unsigned short lb = f2bf(v - hf);
        L2hi[(size_t)col * 512 + k] = (short)hb;
        L2lo[(size_t)col * 512 + k] = (short)lb;
    }
}

// ---------------- GEMM1: t1s = (x @ W1) * dinv[r] ----------------
__global__ __launch_bounds__(256)
void k_gemm1(const float* __restrict__ A, const float* __restrict__ W,
             const float* __restrict__ dinv, float* __restrict__ t1s, int M) {
    __shared__ float xs[64][68];
    const int t  = threadIdx.x;
    const int rb = blockIdx.x * 64;
    const int cg = t & 15, rg = t >> 4;
    const int j0 = cg * 8;

    float acc[4][8] = {};
    for (int kk = 0; kk < 256; kk += 64) {
        __syncthreads();
        for (int i = t; i < 1024; i += 256) {
            int r = i >> 4, q = i & 15;
            float4 v = make_float4(0.f, 0.f, 0.f, 0.f);
            if (rb + r < M)
                v = *(const float4*)(A + (size_t)(rb + r) * 256 + kk + q * 4);
            *(float4*)(&xs[r][q * 4]) = v;
        }
        __syncthreads();
        for (int k = 0; k < 64; ++k) {
            float4 w0 = *(const float4*)(W + (size_t)(kk + k) * 128 + j0);
            float4 w1 = *(const float4*)(W + (size_t)(kk + k) * 128 + j0 + 4);
            float wv[8] = {w0.x, w0.y, w0.z, w0.w, w1.x, w1.y, w1.z, w1.w};
#pragma unroll
            for (int ri = 0; ri < 4; ++ri) {
                float xv = xs[rg * 4 + ri][k];
#pragma unroll
                for (int jj = 0; jj < 8; ++jj)
                    acc[ri][jj] = fmaf(xv, wv[jj], acc[ri][jj]);
            }
        }
    }
#pragma unroll
    for (int ri = 0; ri < 4; ++ri) {
        int r = rb + rg * 4 + ri;
        if (r < M) {
            float dv = dinv[r];
            float4 o0 = make_float4(acc[ri][0] * dv, acc[ri][1] * dv,
                                    acc[ri][2] * dv, acc[ri][3] * dv);
            float4 o1 = make_float4(acc[ri][4] * dv, acc[ri][5] * dv,
                                    acc[ri][6] * dv, acc[ri][7] * dv);
            float* p1 = t1s + (size_t)r * 128 + j0;
            *(float4*)(p1)     = o0;  *(float4*)(p1 + 4) = o1;
        }
    }
}

// ---------------- gather1 + h1 epilogue ----------------
__global__ __launch_bounds__(256)
void k_gather1(const int* __restrict__ deg, const int* __restrict__ off,
               const int* __restrict__ nbr, const float* __restrict__ t1s,
               const float* __restrict__ dinv, const float* __restrict__ b1,
               float* __restrict__ h1, int n) {
    const int lane = threadIdx.x & 63;
    const int node = blockIdx.x * 4 + (threadIdx.x >> 6);
    if (node >= n) return;
    const int dg = deg[node];
    const int o  = off[node];
    const int f0 = lane * 2;
    float2 acc = *(const float2*)(t1s + (size_t)node * 128 + f0);  // self-loop
    int i = 0;
    for (; i + 4 <= dg; i += 4) {
        int r0 = nbr[o + i], r1 = nbr[o + i + 1], r2 = nbr[o + i + 2], r3 = nbr[o + i + 3];
        float2 a0 = *(const float2*)(t1s + (size_t)r0 * 128 + f0);
        float2 a1 = *(const float2*)(t1s + (size_t)r1 * 128 + f0);
        float2 a2 = *(const float2*)(t1s + (size_t)r2 * 128 + f0);
        float2 a3 = *(const float2*)(t1s + (size_t)r3 * 128 + f0);
        acc.x += a0.x + a1.x + a2.x + a3.x;
        acc.y += a0.y + a1.y + a2.y + a3.y;
    }
    for (; i < dg; ++i) {
        int r = nbr[o + i];
        float2 a = *(const float2*)(t1s + (size_t)r * 128 + f0);
        acc.x += a.x; acc.y += a.y;
    }
    float dv = dinv[node];
    float2 b = *(const float2*)(b1 + f0);
    float2 hv;
    hv.x = fmaxf(fmaf(acc.x, dv, b.x), 0.f);
    hv.y = fmaxf(fmaf(acc.y, dv, b.y), 0.f);
    *(float2*)(h1 + (size_t)node * 128 + f0) = hv;
}

// ---------------- GEMM2: t2s = (h1 @ W2) * dinv ----------------
__global__ __launch_bounds__(256)
void k_gemm2(const float* __restrict__ h1, const float* __restrict__ W2,
             const float* __restrict__ dinv, float* __restrict__ t2s, int n) {
    __shared__ float ws[128 * 12];
    int t = threadIdx.x;
    for (int i = t; i < 128 * 12; i += 256) ws[i] = W2[i];
    __syncthreads();
    int node = blockIdx.x * 256 + t;
    if (node >= n) return;
    const float4* hp = (const float4*)(h1 + (size_t)node * 128);
    float acc[12] = {};
    for (int k4 = 0; k4 < 32; ++k4) {
        float4 hv = hp[k4];
        float h[4] = {hv.x, hv.y, hv.z, hv.w};
#pragma unroll
        for (int q = 0; q < 4; ++q) {
            int k = k4 * 4 + q;
#pragma unroll
            for (int j = 0; j < 12; ++j)
                acc[j] = fmaf(h[q], ws[k * 12 + j], acc[j]);
        }
    }
    float dv = dinv[node];
    float* p1 = t2s + (size_t)node * 12;
#pragma unroll
    for (int j = 0; j < 12; ++j) p1[j] = acc[j] * dv;
}

// ---------------- fused MLP with split-bf16 MFMA for layer 2 ----------------
// 64 nodes/block, 512 threads (8 waves). Wave w: 64 rows x 64 cols (cols w*64..).
// Layer2 GEMM: C[64x512] = h3[64x512] @ L2[512x512] via
// A_hi*B_hi + A_lo*B_hi + A_hi*B_lo (bf16 MFMA 16x16x32, fp32 acc).
// acc/lane = 16 f32x4 = 64 VGPR -> no spills (round-4 lesson).
__global__ __launch_bounds__(512, 2)
void k_mlp(const int* __restrict__ deg, const int* __restrict__ off,
           const int* __restrict__ nbr, const float* __restrict__ t2s,
           const float* __restrict__ dinv, const float* __restrict__ b2,
           const float* __restrict__ L1, const float* __restrict__ lb1,
           const short* __restrict__ L2hi, const short* __restrict__ L2lo,
           const float* __restrict__ lb2,
           const float* __restrict__ L3, const float* __restrict__ lb3,
           float* __restrict__ out, int n) {
    __shared__ float h2s[64][13];
    __shared__ short Ahi[64 * 128];      // h3 chunk, bf16 hi, XOR-swizzled rows
    __shared__ short Alo[64 * 128];      // h3 chunk, bf16 lo
    __shared__ float parts[8][64][2];
    const int t  = threadIdx.x;
    const int nb = blockIdx.x * 64;

    // ---- phase 0: gather2 + h2 = relu(dinv*(t2s[self]+sum t2s[nbr]) + b2)
    for (int idx = t; idx < 768; idx += 512) {
        int ni = idx / 12, j = idx % 12;
        int node = nb + ni;
        float v = 0.f;
        if (node < n) {
            int dg = deg[node], o = off[node];
            float acc = t2s[(size_t)node * 12 + j];   // self-loop
            for (int i = 0; i < dg; ++i)
                acc += t2s[(size_t)nbr[o + i] * 12 + j];
            v = fmaxf(fmaf(acc, dinv[node], b2[j]), 0.f);
        }
        h2s[ni][j] = v;
    }
    __syncthreads();

    const int lane = t & 63, wid = t >> 6;
    const int wcb  = wid * 64;           // wave's column base (64 cols)
    const int p1node = t >> 3, p1jg = t & 7;   // phase1: node, 16-col group

    float h2r[12];
#pragma unroll
    for (int q = 0; q < 12; ++q) h2r[q] = h2s[p1node][q];

    f32x4 acc[4][4];
#pragma unroll
    for (int mt = 0; mt < 4; ++mt)
#pragma unroll
        for (int nf = 0; nf < 4; ++nf) acc[mt][nf] = 0.f;

    for (int ch = 0; ch < 4; ++ch) {
        const int cb = ch * 128;
        // ---- phase 1: h3 chunk (128 cols) -> bf16 hi/lo in swizzled LDS
        // thread computes j = cb + p1jg*16 + [0,16) for node p1node
#pragma unroll
        for (int i8 = 0; i8 < 2; ++i8) {
            const int j0 = cb + p1jg * 16 + i8 * 8;
            float4 a0 = *(const float4*)(lb1 + j0);
            float4 a1 = *(const float4*)(lb1 + j0 + 4);
            float v[8] = {a0.x, a0.y, a0.z, a0.w, a1.x, a1.y, a1.z, a1.w};
#pragma unroll
            for (int q = 0; q < 12; ++q) {
                float4 w0 = *(const float4*)(L1 + q * 512 + j0);
                float4 w1 = *(const float4*)(L1 + q * 512 + j0 + 4);
                float hq = h2r[q];
                v[0] = fmaf(hq, w0.x, v[0]); v[1] = fmaf(hq, w0.y, v[1]);
                v[2] = fmaf(hq, w0.z, v[2]); v[3] = fmaf(hq, w0.w, v[3]);
                v[4] = fmaf(hq, w1.x, v[4]); v[5] = fmaf(hq, w1.y, v[5]);
                v[6] = fmaf(hq, w1.z, v[6]); v[7] = fmaf(hq, w1.w, v[7]);
            }
            short8 hv, lv;
#pragma unroll
            for (int e = 0; e < 8; ++e) {
                float f = fmaxf(v[e], 0.f);
                unsigned short hb = f2bf(f);
                float hf = bf2f(hb);
                unsigned short lb = f2bf(f - hf);
                hv[e] = (short)hb; lv[e] = (short)lb;
            }
            const int wb = p1node * 256 + ((p1jg * 32 + i8 * 16) ^ ((p1node & 7) << 4));
            *(short8*)((char*)Ahi + wb) = hv;
            *(short8*)((char*)Alo + wb) = lv;
        }
        __syncthreads();

        // ---- phase 2: MFMA over this K-chunk (4 k-steps of 32)
#pragma unroll
        for (int ks = 0; ks < 4; ++ks) {
            short8 ah[4], al[4];
            const int abase = ks * 64 + ((lane >> 4) << 4);   // byte within row
#pragma unroll
            for (int mt = 0; mt < 4; ++mt) {
                int row = mt * 16 + (lane & 15);
                int boff = row * 256 + (abase ^ ((row & 7) << 4));
                ah[mt] = *(const short8*)((const char*)Ahi + boff);
                al[mt] = *(const short8*)((const char*)Alo + boff);
            }
            const int kg = cb + ks * 32 + ((lane >> 4) << 3);
            short8 bh[4], bl[4];
#pragma unroll
            for (int f = 0; f < 4; ++f) {
                int col = wcb + f * 16 + (lane & 15);
                bh[f] = *(const short8*)(L2hi + (size_t)col * 512 + kg);
                bl[f] = *(const short8*)(L2lo + (size_t)col * 512 + kg);
            }
#pragma unroll
            for (int f = 0; f < 4; ++f) {
#pragma unroll
                for (int mt = 0; mt < 4; ++mt) {
                    f32x4 a = acc[mt][f];
                    a = __builtin_amdgcn_mfma_f32_16x16x32_bf16(ah[mt], bh[f], a, 0, 0, 0);
                    a = __builtin_amdgcn_mfma_f32_16x16x32_bf16(al[mt], bh[f], a, 0, 0, 0);
                    a = __builtin_amdgcn_mfma_f32_16x16x32_bf16(ah[mt], bl[f], a, 0, 0, 0);
                    acc[mt][f] = a;
                }
            }
        }
        __syncthreads();
    }

    // ---- epilogue: h4 = relu(acc + lb2), out-partial = h4 @ L3
    float po[4][4][2];
#pragma unroll
    for (int mt = 0; mt < 4; ++mt)
#pragma unroll
        for (int r = 0; r < 4; ++r) { po[mt][r][0] = 0.f; po[mt][r][1] = 0.f; }
#pragma unroll
    for (int nf = 0; nf < 4; ++nf) {
        int col = wcb + nf * 16 + (lane & 15);
        float bb = lb2[col];
        float2 l3 = *(const float2*)(L3 + (size_t)col * 2);
#pragma unroll
        for (int mt = 0; mt < 4; ++mt)
#pragma unroll
            for (int r = 0; r < 4; ++r) {
                float h4 = fmaxf(acc[mt][nf][r] + bb, 0.f);
                po[mt][r][0] = fmaf(h4, l3.x, po[mt][r][0]);
                po[mt][r][1] = fmaf(h4, l3.y, po[mt][r][1]);
            }
    }
    // reduce over the 16 col-lanes (lane&15); stays within lane>>4 group
#pragma unroll
    for (int ofs = 1; ofs <= 8; ofs <<= 1) {
#pragma unroll
        for (int mt = 0; mt < 4; ++mt)
#pragma unroll
            for (int r = 0; r < 4; ++r) {
                po[mt][r][0] += __shfl_xor(po[mt][r][0], ofs, 64);
                po[mt][r][1] += __shfl_xor(po[mt][r][1], ofs, 64);
            }
    }
    const int g = lane >> 4;
    if ((lane & 15) == 0) {
#pragma unroll
        for (int mt = 0; mt < 4; ++mt)
#pragma unroll
            for (int r = 0; r < 4; ++r) {
                parts[wid][mt * 16 + g * 4 + r][0] = po[mt][r][0];
                parts[wid][mt * 16 + g * 4 + r][1] = po[mt][r][1];
            }
    }
    __syncthreads();
    if (t < 128) {
        int nl = t >> 1, c = t & 1;
        int node = nb + nl;
        if (node < n) {
            float s = lb3[c];
#pragma unroll
            for (int w = 0; w < 8; ++w) s += parts[w][nl][c];
            out[(size_t)node * 2 + c] = s;
        }
    }
}

extern "C" void kernel_launch(void* const* d_in, const int* in_sizes, int n_in,
                              void* d_out, int out_size, void* d_ws, size_t ws_size,
                              hipStream_t stream) {
    const float* x   = (const float*)d_in[0];
    const int*   ei  = (const int*)d_in[1];
    const float* W1  = (const float*)d_in[2];
    const float* b1  = (const float*)d_in[3];
    const float* W2  = (const float*)d_in[4];
    const float* b2  = (const float*)d_in[5];
    const float* L1  = (const float*)d_in[6];
    const float* lb1 = (const float*)d_in[7];
    const float* L2w = (const float*)d_in[8];
    const float* lb2 = (const float*)d_in[9];
    const float* L3  = (const float*)d_in[10];
    const float* lb3 = (const float*)d_in[11];
    float* out = (float*)d_out;

    const int N = in_sizes[0] / 256;
    const int E = in_sizes[1] / 2;
    const int* rowp = ei;       // edge_index[0]
    const int* colp = ei + E;   // edge_index[1]

    char* ws = (char*)d_ws;
    int*   deg    = (int*)ws;                       // N
    int*   cursor = deg + N;                        // N
    int*   offp   = cursor + N;                     // N
    float* dinv   = (float*)(offp + N);             // N
    int*   nbr    = (int*)(dinv + N);               // E
    float* t1s    = (float*)(nbr + E);              // N*128
    float* h1     = t1s + (size_t)N * 128;          // N*128
    float* t2s    = h1 + (size_t)N * 128;           // N*12
    short* L2hi   = (short*)(t2s + (size_t)N * 12); // 512*512
    short* L2lo   = L2hi + 512 * 512;               // 512*512

    k_init  <<<(N + 255) / 256, 256, 0, stream>>>(deg, cursor, N);
    k_count <<<(E + 255) / 256, 256, 0, stream>>>(colp, deg, E);
    k_dinv  <<<(N + 255) / 256, 256, 0, stream>>>(deg, dinv, N);
    k_scan  <<<1, 1024, 0, stream>>>(deg, offp, N);
    k_fill  <<<(E + 255) / 256, 256, 0, stream>>>(rowp, colp, offp, cursor, nbr, E);
    k_cvtL2 <<<512, 256, 0, stream>>>(L2w, L2hi, L2lo);

    k_gemm1   <<<(N + 63) / 64, 256, 0, stream>>>(x, W1, dinv, t1s, N);
    k_gather1 <<<(N + 3) / 4, 256, 0, stream>>>(deg, offp, nbr, t1s, dinv, b1, h1, N);
    k_gemm2   <<<(N + 255) / 256, 256, 0, stream>>>(h1, W2, dinv, t2s, N);
    k_mlp     <<<(N + 63) / 64, 512, 0, stream>>>(deg, offp, nbr, t2s, dinv, b2,
                                                  L1, lb1, L2hi, L2lo, lb2,
                                                  L3, lb3, out, N);
}